// Round 1
// baseline (1346.376 us; speedup 1.0000x reference)
//
#include <hip/hip_runtime.h>
#include <stdint.h>
#include <stddef.h>

typedef __attribute__((ext_vector_type(8))) short short8;
typedef __attribute__((ext_vector_type(4))) float floatx4;

#define HW_IN  (64 * 64)   // input H*W
#define HW_GO  (62 * 62)   // grad_output Ho*Wo
#define MT 128             // C_out tile per block
#define NT 32              // C_in tile per block
#define UNITS_PER_CHUNK 32
#define NCHUNK 62          // 62 chunks * 32 units = 1984 = 32 imgs * 62 rows

__device__ __forceinline__ short f2bf(float f) {
    // round-to-nearest-even fp32 -> bf16 (inputs are finite normals)
    uint32_t u = __float_as_uint(f);
    u += 0x7FFFu + ((u >> 16) & 1u);
    return (short)(u >> 16);
}

__global__ __launch_bounds__(256, 1) void convbw_kernel(
    const float* __restrict__ inp,   // (32,128,64,64)
    const float* __restrict__ gout,  // (32,256,62,62)
    float* __restrict__ out)         // (256,128,3,3) pre-zeroed
{
    // LDS tiles. Row stride 72 shorts = 144 B = 36 dwords -> rows r and r+8
    // share banks (2-way, free per m136); 144 % 16 == 0 keeps short8 aligned.
    __shared__ __align__(16) short GO_sh[128][72];
    __shared__ __align__(16) short X_sh[3][3][32][72];

    const int tid  = threadIdx.x;
    const int lane = tid & 63;
    const int wave = tid >> 6;      // 0..3
    const int l15  = lane & 15;
    const int quad = lane >> 4;

    const int chunk = blockIdx.x;         // 0..61
    const int Mbase = blockIdx.y * MT;    // 0 or 128
    const int Cbase = blockIdx.z * NT;    // 0,32,64,96

    // Zero all LDS once: the never-written pad cells (j>=62 in GO, the
    // kw-shift tail cells in X, the stride pad) must be 0/finite forever.
    {
        int* g = (int*)&GO_sh[0][0];
        for (int k = tid; k < 128 * 72 / 2; k += 256) g[k] = 0;
        int* x = (int*)&X_sh[0][0][0][0];
        for (int k = tid; k < 3 * 3 * 32 * 72 / 2; k += 256) x[k] = 0;
    }

    floatx4 acc[2][2][9];
#pragma unroll
    for (int mi = 0; mi < 2; ++mi)
#pragma unroll
        for (int ni = 0; ni < 2; ++ni)
#pragma unroll
            for (int t = 0; t < 9; ++t)
                acc[mi][ni][t] = (floatx4){0.f, 0.f, 0.f, 0.f};

    __syncthreads();

    for (int uu = 0; uu < UNITS_PER_CHUNK; ++uu) {
        const int u     = chunk * UNITS_PER_CHUNK + uu;
        const int n_img = u / 62;
        const int i     = u - n_img * 62;   // output row index 0..61

        // --- stage grad_output tile: GO_sh[o][j] = gout[n, Mbase+o, i, j]
        {
            const float* bg = gout + (size_t)(n_img * 256 + Mbase) * HW_GO
                                   + (size_t)i * 62;
            if (lane < 62) {
#pragma unroll 4
                for (int rr = 0; rr < 32; ++rr) {
                    const int o_loc = rr * 4 + wave;
                    GO_sh[o_loc][lane] = f2bf(bg[(size_t)o_loc * HW_GO + lane]);
                }
            }
        }
        // --- stage input tile, 9 pre-shifted copies:
        // X_sh[kh][kw][c][j] = inp[n, Cbase+c, i+kh, j+kw]
        {
            const float* bi = inp + (size_t)(n_img * 128 + Cbase) * HW_IN
                                  + (size_t)i * 64;
#pragma unroll 4
            for (int rr = 0; rr < 24; ++rr) {
                const int row   = rr * 4 + wave;  // 0..95 = kh*32 + c
                const int c_loc = row & 31;
                const int kh    = row >> 5;
                const short bv  = f2bf(bi[(size_t)c_loc * HW_IN + kh * 64 + lane]);
#pragma unroll
                for (int kw = 0; kw < 3; ++kw) {
                    const int j = lane - kw;      // w = j + kw
                    if (j >= 0) X_sh[kh][kw][c_loc][j] = bv;
                }
            }
        }
        __syncthreads();

        // --- MFMA: C[o][c] += sum_j GO[o][j] * X[c][j], per tap
#pragma unroll
        for (int ks = 0; ks < 2; ++ks) {
            const int kc = ks * 32 + quad * 8;
            const short8 a0 = *(const short8*)&GO_sh[wave * 32 + l15][kc];
            const short8 a1 = *(const short8*)&GO_sh[wave * 32 + 16 + l15][kc];
#pragma unroll
            for (int kh = 0; kh < 3; ++kh) {
#pragma unroll
                for (int kw = 0; kw < 3; ++kw) {
                    const int t = kh * 3 + kw;
#pragma unroll
                    for (int ni = 0; ni < 2; ++ni) {
                        const short8 b =
                            *(const short8*)&X_sh[kh][kw][ni * 16 + l15][kc];
                        acc[0][ni][t] = __builtin_amdgcn_mfma_f32_16x16x32_bf16(
                            a0, b, acc[0][ni][t], 0, 0, 0);
                        acc[1][ni][t] = __builtin_amdgcn_mfma_f32_16x16x32_bf16(
                            a1, b, acc[1][ni][t], 0, 0, 0);
                    }
                }
            }
        }
        __syncthreads();
    }

    // --- epilogue: split-K partials -> global via atomicAdd
    // C/D layout (m89/m91): col = lane&15, row = quad*4 + reg
#pragma unroll
    for (int mi = 0; mi < 2; ++mi) {
        const int o_base = Mbase + wave * 32 + mi * 16 + quad * 4;
#pragma unroll
        for (int ni = 0; ni < 2; ++ni) {
            const int c = Cbase + ni * 16 + l15;
#pragma unroll
            for (int t = 0; t < 9; ++t) {
#pragma unroll
                for (int r = 0; r < 4; ++r) {
                    atomicAdd(out + (size_t)(o_base + r) * 1152 + c * 9 + t,
                              acc[mi][ni][t][r]);
                }
            }
        }
    }
}

extern "C" void kernel_launch(void* const* d_in, const int* in_sizes, int n_in,
                              void* d_out, int out_size, void* d_ws, size_t ws_size,
                              hipStream_t stream) {
    const float* inp  = (const float*)d_in[0];   // 'input'
    const float* gout = (const float*)d_in[1];   // 'grad_output'
    float* out = (float*)d_out;

    // harness poisons d_out with 0xAA before every launch; we accumulate
    hipMemsetAsync(d_out, 0, (size_t)out_size * sizeof(float), stream);

    dim3 grid(NCHUNK, 256 / MT, 128 / NT);  // (62, 2, 4) = 496 blocks
    convbw_kernel<<<grid, 256, 0, stream>>>(inp, gout, out);
}

// Round 2
// 408.641 us; speedup vs baseline: 3.2948x; 3.2948x over previous
//
#include <hip/hip_runtime.h>
#include <stdint.h>
#include <stddef.h>

typedef __attribute__((ext_vector_type(8))) short short8;
typedef __attribute__((ext_vector_type(4))) float floatx4;
typedef __attribute__((ext_vector_type(2))) float floatx2;

#define HW_IN   4096       // 64*64
#define HW_GO   3844       // 62*62
#define OUT_ELEMS 294912   // 256*128*9
#define NCHUNK 62
#define UNITS  32          // units (n,i rows) per chunk

// round-to-nearest-even fp32 pair -> packed bf16x2
__device__ __forceinline__ uint32_t pk_bf16(float a, float b) {
    uint32_t ua = __float_as_uint(a); ua += 0x7FFFu + ((ua >> 16) & 1u);
    uint32_t ub = __float_as_uint(b); ub += 0x7FFFu + ((ub >> 16) & 1u);
    return (ua >> 16) | (ub & 0xFFFF0000u);
}

// Phase 1: per-chunk partial GEMM. Each block: M=128 (C_out), N=32 (C_in),
// 9 taps, K = 32 units x 64 (Wo=62 padded to 64 with A-zeros).
// USE_ATOMIC=false: writes partial tile to dst[chunk*OUT_ELEMS + ...].
// USE_ATOMIC=true : atomicAdd directly into pre-zeroed output (ws fallback).
template<bool USE_ATOMIC>
__global__ __launch_bounds__(256, 1) void convbw_kernel(
    const float* __restrict__ inp,   // (32,128,64,64)
    const float* __restrict__ gout,  // (32,256,62,62)
    float* __restrict__ dst)
{
    // Row stride 72 shorts = 144 B: short8 reads stay 16B-aligned, rows
    // alias banks 2-way (free, m136). Pad cols 64..71 never read.
    __shared__ __align__(16) short GO_sh[128][72];        // A: GO[o][j]
    __shared__ __align__(16) short X_sh[3][3][32][72];    // B: 9 shifted copies

    const int tid  = threadIdx.x;
    const int lane = tid & 63;
    const int wave = tid >> 6;
    const int l15  = lane & 15;
    const int quad = lane >> 4;

    const int Mbase = blockIdx.x * 128;   // 0,128
    const int Cbase = blockIdx.y * 32;    // 0,32,64,96
    const int chunk = blockIdx.z;         // 0..61

    // staging thread maps
    const int gl    = tid & 31;   // GO: 32 lanes x float2 = 64 cols/row
    const int grow0 = tid >> 5;   // 8 GO rows per pass, 16 passes
    const int xl    = tid & 15;   // X: 16 lanes x float4 = 64 cols/row
    const int xrow0 = tid >> 4;   // 16 X rows per pass, 6 passes

    floatx2 go_r[16];
    floatx4 x_r[6];

    auto issue_loads = [&](int u) {
        const int n_img = u / 62;
        const int i     = u - n_img * 62;
        const float* bg = gout + (size_t)(n_img * 256 + Mbase) * HW_GO + i * 62;
        const float* bi = inp  + (size_t)(n_img * 128 + Cbase) * HW_IN + i * 64;
#pragma unroll
        for (int p = 0; p < 16; ++p) {
            const int row = grow0 + p * 8;           // 0..127
            // 8B-aligned: bases are 8B multiples, gl*2 floats = 8B step.
            // gl==31 reads cols 62,63 (next row's data, in-bounds) -> zeroed
            go_r[p] = *(const floatx2*)(bg + (size_t)row * HW_GO + gl * 2);
        }
#pragma unroll
        for (int p = 0; p < 6; ++p) {
            const int row = xrow0 + p * 16;          // 0..95 = kh*32 + c
            const int c = row & 31, kh = row >> 5;
            x_r[p] = *(const floatx4*)(bi + (size_t)c * HW_IN + kh * 64 + xl * 4);
        }
    };

    auto flush_to_lds = [&]() {
#pragma unroll
        for (int p = 0; p < 16; ++p) {
            const int row = grow0 + p * 8;
            uint32_t v = pk_bf16(go_r[p].x, go_r[p].y);
            if (gl == 31) v = 0;   // A cols 62,63 must be zero (K pad)
            *(uint32_t*)&GO_sh[row][gl * 2] = v;
        }
#pragma unroll
        for (int p = 0; p < 6; ++p) {
            const int row = xrow0 + p * 16;
            const int c = row & 31, kh = row >> 5;
            // this lane holds w = 4*xl .. 4*xl+3 of the row
            uint32_t lo = pk_bf16(x_r[p].x, x_r[p].y);   // {w0,w1}
            uint32_t hi = pk_bf16(x_r[p].z, x_r[p].w);   // {w2,w3}
            // neighbor's first pair gives w4 (xl==15: garbage-but-finite,
            // lands only at j>=62 where A is zero)
            uint32_t nlo = (uint32_t)__shfl((int)lo, (lane + 1) & 63, 64);
            // copy kw stores X_sh[..][kw][c][j=4*xl..] = x[w = j+kw]
            uint2 v0 = {lo, hi};
            uint2 v1 = {(lo >> 16) | (hi << 16), (hi >> 16) | (nlo << 16)};
            uint2 v2 = {hi, nlo};
            *(uint2*)&X_sh[kh][0][c][xl * 4] = v0;
            *(uint2*)&X_sh[kh][1][c][xl * 4] = v1;
            *(uint2*)&X_sh[kh][2][c][xl * 4] = v2;
        }
    };

    floatx4 acc[2][2][9];
#pragma unroll
    for (int mi = 0; mi < 2; ++mi)
#pragma unroll
        for (int ni = 0; ni < 2; ++ni)
#pragma unroll
            for (int t = 0; t < 9; ++t)
                acc[mi][ni][t] = (floatx4){0.f, 0.f, 0.f, 0.f};

    issue_loads(chunk * UNITS);   // prologue prefetch

#pragma unroll 1
    for (int uu = 0; uu < UNITS; ++uu) {
        flush_to_lds();                               // regs(u) -> LDS
        if (uu + 1 < UNITS) issue_loads(chunk * UNITS + uu + 1);  // prefetch u+1
        __syncthreads();                              // staging visible

#pragma unroll
        for (int ks = 0; ks < 2; ++ks) {
            const int kc = ks * 32 + quad * 8;
            const short8 a0 = *(const short8*)&GO_sh[wave * 32 + l15][kc];
            const short8 a1 = *(const short8*)&GO_sh[wave * 32 + 16 + l15][kc];
#pragma unroll
            for (int kh = 0; kh < 3; ++kh) {
#pragma unroll
                for (int kw = 0; kw < 3; ++kw) {
                    const int t = kh * 3 + kw;
#pragma unroll
                    for (int ni = 0; ni < 2; ++ni) {
                        const short8 b =
                            *(const short8*)&X_sh[kh][kw][ni * 16 + l15][kc];
                        acc[0][ni][t] = __builtin_amdgcn_mfma_f32_16x16x32_bf16(
                            a0, b, acc[0][ni][t], 0, 0, 0);
                        acc[1][ni][t] = __builtin_amdgcn_mfma_f32_16x16x32_bf16(
                            a1, b, acc[1][ni][t], 0, 0, 0);
                    }
                }
            }
        }
        __syncthreads();   // MFMA done before next flush overwrites LDS
    }

    // Epilogue. C/D layout (m89/m91): col = lane&15, row = quad*4 + reg.
    float* base = USE_ATOMIC ? dst : dst + (size_t)chunk * OUT_ELEMS;
#pragma unroll
    for (int mi = 0; mi < 2; ++mi) {
        const int o_base = Mbase + wave * 32 + mi * 16 + quad * 4;
#pragma unroll
        for (int ni = 0; ni < 2; ++ni) {
            const int c = Cbase + ni * 16 + l15;
#pragma unroll
            for (int t = 0; t < 9; ++t) {
#pragma unroll
                for (int r = 0; r < 4; ++r) {
                    const size_t off = (size_t)(o_base + r) * 1152 + c * 9 + t;
                    if (USE_ATOMIC) atomicAdd(base + off, acc[mi][ni][t][r]);
                    else            base[off] = acc[mi][ni][t][r];
                }
            }
        }
    }
}

// Phase 2: out[e] = sum over 62 chunk partials. 73 MB coalesced read.
__global__ __launch_bounds__(256) void reduce_kernel(
    const floatx4* __restrict__ ws, floatx4* __restrict__ out)
{
    const int idx = blockIdx.x * 256 + threadIdx.x;   // < 73728
    floatx4 s = {0.f, 0.f, 0.f, 0.f};
#pragma unroll 2
    for (int ch = 0; ch < NCHUNK; ++ch)
        s += ws[(size_t)ch * (OUT_ELEMS / 4) + idx];
    out[idx] = s;
}

extern "C" void kernel_launch(void* const* d_in, const int* in_sizes, int n_in,
                              void* d_out, int out_size, void* d_ws, size_t ws_size,
                              hipStream_t stream) {
    const float* inp  = (const float*)d_in[0];   // 'input'
    const float* gout = (const float*)d_in[1];   // 'grad_output'
    float* out = (float*)d_out;

    const size_t ws_need = (size_t)NCHUNK * OUT_ELEMS * sizeof(float); // 73.1 MB
    dim3 grid(2, 4, NCHUNK);   // x,y = output tile (shared-data blocks adjacent)

    if (ws_size >= ws_need) {
        float* ws = (float*)d_ws;
        convbw_kernel<false><<<grid, 256, 0, stream>>>(inp, gout, ws);
        reduce_kernel<<<OUT_ELEMS / 4 / 256, 256, 0, stream>>>(
            (const floatx4*)ws, (floatx4*)out);
    } else {
        // fallback: atomic accumulation into zeroed output
        hipMemsetAsync(d_out, 0, (size_t)out_size * sizeof(float), stream);
        convbw_kernel<true><<<grid, 256, 0, stream>>>(inp, gout, out);
    }
}

// Round 3
// 351.691 us; speedup vs baseline: 3.8283x; 1.1619x over previous
//
#include <hip/hip_runtime.h>
#include <stdint.h>
#include <stddef.h>

typedef __attribute__((ext_vector_type(8))) short short8;
typedef __attribute__((ext_vector_type(4))) float floatx4;
typedef __attribute__((ext_vector_type(2))) float floatx2;
typedef __attribute__((ext_vector_type(2))) unsigned int uintx2;

#define HW_IN   4096       // 64*64
#define HW_GO   3844       // 62*62
#define OUT_ELEMS 294912   // 256*128*9
#define NCHUNK 62
#define UNITS  32

// ws layout (bytes):
//   [0, 73138176)               : fp32 partials, 62 chunks x OUT_ELEMS
//   [73138176, 146276352)       : GO_ws bf16 [n][i][o=256][72]  (cols>=62 zero)
//   [146276352, 179830784)      : X_ws  bf16 [n][c=128][h=64][w=64]
#define PART_BYTES  73138176ull
#define GOWS_BYTES  73138176ull
#define XWS_BYTES   33554432ull
#define WS_FULL     (PART_BYTES + GOWS_BYTES + XWS_BYTES)

__device__ __forceinline__ uint32_t pk_bf16(float a, float b) {
    uint32_t ua = __float_as_uint(a); ua += 0x7FFFu + ((ua >> 16) & 1u);
    uint32_t ub = __float_as_uint(b); ub += 0x7FFFu + ((ub >> 16) & 1u);
    return (ua >> 16) | (ub & 0xFFFF0000u);
}

__device__ __forceinline__ void load_lds16(const void* g, void* l) {
    __builtin_amdgcn_global_load_lds(
        (const __attribute__((address_space(1))) void*)g,
        (__attribute__((address_space(3))) void*)l, 16, 0, 0);
}

// ---- pre-pass 1: gout fp32 -> GO_ws bf16 [n][i][256][72], pad cols zero
__global__ __launch_bounds__(256) void go_conv(
    const float* __restrict__ gout, uint32_t* __restrict__ go_ws)
{
    const uint32_t t = blockIdx.x * 256 + threadIdx.x;  // < 18,284,544
    const uint32_t row = t / 36;          // (n*62+i)*256 + o
    const uint32_t j   = t - row * 36;    // dword within 72-short row
    const uint32_t o   = row & 255;
    const uint32_t ni  = row >> 8;        // n*62+i
    const uint32_t n   = ni / 62;
    const uint32_t i   = ni - n * 62;
    uint32_t v = 0;
    if (j < 31) {
        const float* g = gout + (size_t)(n * 256 + o) * HW_GO + i * 62 + 2 * j;
        v = pk_bf16(g[0], g[1]);
    }
    go_ws[t] = v;
}

// ---- pre-pass 2: input fp32 -> X_ws bf16 (plain elementwise)
__global__ __launch_bounds__(256) void x_conv(
    const floatx4* __restrict__ inp, uintx2* __restrict__ x_ws)
{
    const uint32_t t = blockIdx.x * 256 + threadIdx.x;  // < 4,194,304
    floatx4 v = inp[t];
    uintx2 o;
    o.x = pk_bf16(v.x, v.y);
    o.y = pk_bf16(v.z, v.w);
    x_ws[t] = o;
}

// ---- main: per-chunk partial GEMM, bf16 inputs from ws
__global__ __launch_bounds__(256, 2) void convbw2_kernel(
    const short* __restrict__ go_ws,   // [n][i][256][72] bf16
    const short* __restrict__ x_ws,    // [n][128][64][64] bf16
    float* __restrict__ dst)           // partials, chunk-major
{
    __shared__ __align__(16) short GO_sh[2][128][72];   // 36864 B (dbuf)
    __shared__ __align__(16) short X_sh[3][3][32][72];  // 41472 B

    const int tid  = threadIdx.x;
    const int lane = tid & 63;
    const int wave = tid >> 6;
    const int l15  = lane & 15;
    const int quad = lane >> 4;

    const int Mbase = blockIdx.x * 128;   // 0,128
    const int Cbase = blockIdx.y * 32;    // 0..96
    const int chunk = blockIdx.z;         // 0..61

    const int xl    = tid & 15;           // 16 lanes x 4 bf16 per X row
    const int xrow0 = tid >> 4;           // 16 rows/pass, 6 passes (96 rows)

    uintx2 x_r[6];

    auto load_x = [&](int u) {
        const int n_img = u / 62;
        const int i     = u - n_img * 62;
        const short* bx = x_ws + ((size_t)(n_img * 128 + Cbase) << 12)
                               + ((size_t)i << 6) + xl * 4;
#pragma unroll
        for (int p = 0; p < 6; ++p) {
            const int row = xrow0 + p * 16;       // kh*32 + c
            const int c = row & 31, kh = row >> 5;
            x_r[p] = *(const uintx2*)(bx + ((size_t)c << 12) + (kh << 6));
        }
    };

    auto dma_go = [&](int u, int buf) {
        const int n_img = u / 62;
        const int i     = u - n_img * 62;
        const short* src = go_ws + ((size_t)(n_img * 62 + i) * 256 + Mbase) * 72;
        short* d = &GO_sh[buf][0][0];
#pragma unroll
        for (int k = wave; k < 18; k += 4)        // 18 x 1KB = 128x72x2 B
            load_lds16(src + k * 512 + lane * 8, d + k * 512);
    };

    auto flush_x = [&]() {
#pragma unroll
        for (int p = 0; p < 6; ++p) {
            const int row = xrow0 + p * 16;
            const int c = row & 31, kh = row >> 5;
            const uint32_t d0 = x_r[p].x, d1 = x_r[p].y;
            // neighbor lane's first dword supplies shorts w+4, w+5.
            // xl==15 gets garbage (wraps) -> lands only at j>=62 where A==0.
            const uint32_t dn = (uint32_t)__shfl((int)d0, (lane + 1) & 63);
            uintx2 w0 = {d0, d1};
            uintx2 w1 = {(d0 >> 16) | (d1 << 16), (d1 >> 16) | (dn << 16)};
            uintx2 w2 = {d1, dn};
            short* base = &X_sh[kh][0][c][xl * 4];
            *(uintx2*)(base)            = w0;     // kw=0
            *(uintx2*)(base + 2304)     = w1;     // kw=1 (stride 32*72)
            *(uintx2*)(base + 4608)     = w2;     // kw=2
        }
    };

    floatx4 acc[2][2][9];
#pragma unroll
    for (int mi = 0; mi < 2; ++mi)
#pragma unroll
        for (int ni = 0; ni < 2; ++ni)
#pragma unroll
            for (int t = 0; t < 9; ++t)
                acc[mi][ni][t] = (floatx4){0.f, 0.f, 0.f, 0.f};

    // prologue: unit 0 into regs / buf0
    load_x(chunk * UNITS);
    dma_go(chunk * UNITS, 0);

#pragma unroll 1
    for (int uu = 0; uu < UNITS; ++uu) {
        flush_x();                 // X regs(u) -> LDS (waits its own vmem)
        __syncthreads();           // X_sh + GO dbuf visible; prev MFMA done

        if (uu + 1 < UNITS) {      // issued AFTER barrier -> overlaps MFMA
            load_x(chunk * UNITS + uu + 1);
            dma_go(chunk * UNITS + uu + 1, (uu + 1) & 1);
        }

        const short* gb = &GO_sh[uu & 1][0][0];
#pragma unroll
        for (int ks = 0; ks < 2; ++ks) {
            const int kc = ks * 32 + quad * 8;
            const short8 a0 = *(const short8*)(gb + (wave * 32 + l15) * 72 + kc);
            const short8 a1 = *(const short8*)(gb + (wave * 32 + 16 + l15) * 72 + kc);
#pragma unroll
            for (int kh = 0; kh < 3; ++kh) {
#pragma unroll
                for (int kw = 0; kw < 3; ++kw) {
                    const int t = kh * 3 + kw;
#pragma unroll
                    for (int ni = 0; ni < 2; ++ni) {
                        const short8 b =
                            *(const short8*)&X_sh[kh][kw][ni * 16 + l15][kc];
                        acc[0][ni][t] = __builtin_amdgcn_mfma_f32_16x16x32_bf16(
                            a0, b, acc[0][ni][t], 0, 0, 0);
                        acc[1][ni][t] = __builtin_amdgcn_mfma_f32_16x16x32_bf16(
                            a1, b, acc[1][ni][t], 0, 0, 0);
                    }
                }
            }
        }
        __syncthreads();   // MFMA reads done; u+1 vmem drained (overlapped)
    }

    // epilogue: C/D layout col=lane&15, row=quad*4+reg (m89/m91)
    float* base = dst + (size_t)chunk * OUT_ELEMS;
#pragma unroll
    for (int mi = 0; mi < 2; ++mi) {
        const int o_base = Mbase + wave * 32 + mi * 16 + quad * 4;
#pragma unroll
        for (int ni = 0; ni < 2; ++ni) {
            const int c = Cbase + ni * 16 + l15;
#pragma unroll
            for (int t = 0; t < 9; ++t)
#pragma unroll
                for (int r = 0; r < 4; ++r)
                    base[(size_t)(o_base + r) * 1152 + c * 9 + t] =
                        acc[mi][ni][t][r];
        }
    }
}

// ================= fallback (R2 path, ws too small for bf16 staging) ======
template<bool USE_ATOMIC>
__global__ __launch_bounds__(256, 1) void convbw_kernel(
    const float* __restrict__ inp, const float* __restrict__ gout,
    float* __restrict__ dst)
{
    __shared__ __align__(16) short GO_sh[128][72];
    __shared__ __align__(16) short X_sh[3][3][32][72];
    const int tid = threadIdx.x, lane = tid & 63, wave = tid >> 6;
    const int l15 = lane & 15, quad = lane >> 4;
    const int Mbase = blockIdx.x * 128, Cbase = blockIdx.y * 32;
    const int chunk = blockIdx.z;
    const int gl = tid & 31, grow0 = tid >> 5, xl = tid & 15, xrow0 = tid >> 4;
    floatx2 go_r[16];
    floatx4 x_r[6];
    auto issue_loads = [&](int u) {
        const int n_img = u / 62, i = u - n_img * 62;
        const float* bg = gout + (size_t)(n_img * 256 + Mbase) * HW_GO + i * 62;
        const float* bi = inp + (size_t)(n_img * 128 + Cbase) * HW_IN + i * 64;
#pragma unroll
        for (int p = 0; p < 16; ++p)
            go_r[p] = *(const floatx2*)(bg + (size_t)(grow0 + p * 8) * HW_GO + gl * 2);
#pragma unroll
        for (int p = 0; p < 6; ++p) {
            const int row = xrow0 + p * 16, c = row & 31, kh = row >> 5;
            x_r[p] = *(const floatx4*)(bi + (size_t)c * HW_IN + kh * 64 + xl * 4);
        }
    };
    auto flush = [&]() {
#pragma unroll
        for (int p = 0; p < 16; ++p) {
            uint32_t v = pk_bf16(go_r[p].x, go_r[p].y);
            if (gl == 31) v = 0;
            *(uint32_t*)&GO_sh[grow0 + p * 8][gl * 2] = v;
        }
#pragma unroll
        for (int p = 0; p < 6; ++p) {
            const int row = xrow0 + p * 16, c = row & 31, kh = row >> 5;
            uint32_t lo = pk_bf16(x_r[p].x, x_r[p].y);
            uint32_t hi = pk_bf16(x_r[p].z, x_r[p].w);
            uint32_t nlo = (uint32_t)__shfl((int)lo, (lane + 1) & 63);
            uintx2 v0 = {lo, hi};
            uintx2 v1 = {(lo >> 16) | (hi << 16), (hi >> 16) | (nlo << 16)};
            uintx2 v2 = {hi, nlo};
            *(uintx2*)&X_sh[kh][0][c][xl * 4] = v0;
            *(uintx2*)&X_sh[kh][1][c][xl * 4] = v1;
            *(uintx2*)&X_sh[kh][2][c][xl * 4] = v2;
        }
    };
    floatx4 acc[2][2][9];
#pragma unroll
    for (int mi = 0; mi < 2; ++mi)
#pragma unroll
        for (int ni = 0; ni < 2; ++ni)
#pragma unroll
            for (int t = 0; t < 9; ++t) acc[mi][ni][t] = (floatx4){0,0,0,0};
    issue_loads(chunk * UNITS);
#pragma unroll 1
    for (int uu = 0; uu < UNITS; ++uu) {
        flush();
        if (uu + 1 < UNITS) issue_loads(chunk * UNITS + uu + 1);
        __syncthreads();
#pragma unroll
        for (int ks = 0; ks < 2; ++ks) {
            const int kc = ks * 32 + quad * 8;
            const short8 a0 = *(const short8*)&GO_sh[wave * 32 + l15][kc];
            const short8 a1 = *(const short8*)&GO_sh[wave * 32 + 16 + l15][kc];
#pragma unroll
            for (int kh = 0; kh < 3; ++kh)
#pragma unroll
                for (int kw = 0; kw < 3; ++kw) {
                    const int t = kh * 3 + kw;
#pragma unroll
                    for (int ni = 0; ni < 2; ++ni) {
                        const short8 b = *(const short8*)&X_sh[kh][kw][ni * 16 + l15][kc];
                        acc[0][ni][t] = __builtin_amdgcn_mfma_f32_16x16x32_bf16(a0, b, acc[0][ni][t], 0, 0, 0);
                        acc[1][ni][t] = __builtin_amdgcn_mfma_f32_16x16x32_bf16(a1, b, acc[1][ni][t], 0, 0, 0);
                    }
                }
        }
        __syncthreads();
    }
    float* base = USE_ATOMIC ? dst : dst + (size_t)chunk * OUT_ELEMS;
#pragma unroll
    for (int mi = 0; mi < 2; ++mi) {
        const int o_base = Mbase + wave * 32 + mi * 16 + quad * 4;
#pragma unroll
        for (int ni = 0; ni < 2; ++ni) {
            const int c = Cbase + ni * 16 + l15;
#pragma unroll
            for (int t = 0; t < 9; ++t)
#pragma unroll
                for (int r = 0; r < 4; ++r) {
                    const size_t off = (size_t)(o_base + r) * 1152 + c * 9 + t;
                    if (USE_ATOMIC) atomicAdd(base + off, acc[mi][ni][t][r]);
                    else base[off] = acc[mi][ni][t][r];
                }
        }
    }
}

__global__ __launch_bounds__(256) void reduce_kernel(
    const floatx4* __restrict__ ws, floatx4* __restrict__ out)
{
    const int idx = blockIdx.x * 256 + threadIdx.x;
    floatx4 s = {0.f, 0.f, 0.f, 0.f};
#pragma unroll 2
    for (int ch = 0; ch < NCHUNK; ++ch)
        s += ws[(size_t)ch * (OUT_ELEMS / 4) + idx];
    out[idx] = s;
}

extern "C" void kernel_launch(void* const* d_in, const int* in_sizes, int n_in,
                              void* d_out, int out_size, void* d_ws, size_t ws_size,
                              hipStream_t stream) {
    const float* inp  = (const float*)d_in[0];
    const float* gout = (const float*)d_in[1];
    float* out = (float*)d_out;
    dim3 grid(2, 4, NCHUNK);

    if (ws_size >= WS_FULL) {
        float* part = (float*)d_ws;
        short* go_ws = (short*)((char*)d_ws + PART_BYTES);
        short* x_ws  = (short*)((char*)d_ws + PART_BYTES + GOWS_BYTES);
        go_conv<<<71424, 256, 0, stream>>>(gout, (uint32_t*)go_ws);
        x_conv<<<16384, 256, 0, stream>>>((const floatx4*)inp, (uintx2*)x_ws);
        convbw2_kernel<<<grid, 256, 0, stream>>>(go_ws, x_ws, part);
        reduce_kernel<<<OUT_ELEMS / 4 / 256, 256, 0, stream>>>(
            (const floatx4*)part, (floatx4*)out);
    } else if (ws_size >= PART_BYTES) {
        float* part = (float*)d_ws;
        convbw_kernel<false><<<grid, 256, 0, stream>>>(inp, gout, part);
        reduce_kernel<<<OUT_ELEMS / 4 / 256, 256, 0, stream>>>(
            (const floatx4*)part, (floatx4*)out);
    } else {
        hipMemsetAsync(d_out, 0, (size_t)out_size * sizeof(float), stream);
        convbw_kernel<true><<<grid, 256, 0, stream>>>(inp, gout, out);
    }
}

// Round 4
// 330.050 us; speedup vs baseline: 4.0793x; 1.0656x over previous
//
#include <hip/hip_runtime.h>
#include <stdint.h>
#include <stddef.h>

typedef __attribute__((ext_vector_type(8))) short short8;
typedef __attribute__((ext_vector_type(4))) float floatx4;
typedef __attribute__((ext_vector_type(2))) float floatx2;
typedef __attribute__((ext_vector_type(2))) unsigned int uintx2;
typedef __attribute__((ext_vector_type(4))) int intx4;

#define HW_IN   4096       // 64*64
#define HW_GO   3844       // 62*62
#define OUT_ELEMS 294912   // 256*128*9
#define NCHUNK 62
#define UNITS  32

// ws layout (bytes):
//   [0, 73138176)          : fp32 partials, 62 chunks x OUT_ELEMS
//   [73138176, 146276352)  : GO_ws bf16 [n][i][o=256][72]  (cols>=62 zero)
//   [146276352, 179830784) : X_ws  bf16 [n][c=128][h=64][w=64], 16B-chunk
//                            XOR-swizzled within each 128B row by (c&7)
#define PART_BYTES  73138176ull
#define GOWS_BYTES  73138176ull
#define XWS_BYTES   33554432ull
#define WS_FULL     (PART_BYTES + GOWS_BYTES + XWS_BYTES)

__device__ __forceinline__ uint32_t pk_bf16(float a, float b) {
    uint32_t ua = __float_as_uint(a); ua += 0x7FFFu + ((ua >> 16) & 1u);
    uint32_t ub = __float_as_uint(b); ub += 0x7FFFu + ((ub >> 16) & 1u);
    return (ua >> 16) | (ub & 0xFFFF0000u);
}

__device__ __forceinline__ void load_lds16(const void* g, void* l) {
    // LDS dest = wave-uniform base + lane*16 (m104/m108); global side per-lane.
    __builtin_amdgcn_global_load_lds(
        (const __attribute__((address_space(1))) void*)g,
        (__attribute__((address_space(3))) void*)l, 16, 0, 0);
}

// ---- pre-pass 1: gout fp32 -> GO_ws bf16 [n][i][256][72], pad cols zero
__global__ __launch_bounds__(256) void go_conv(
    const float* __restrict__ gout, uint32_t* __restrict__ go_ws)
{
    const uint32_t t = blockIdx.x * 256 + threadIdx.x;  // < 18,284,544
    const uint32_t row = t / 36;          // (n*62+i)*256 + o
    const uint32_t j   = t - row * 36;    // dword within 72-short row
    const uint32_t o   = row & 255;
    const uint32_t ni  = row >> 8;
    const uint32_t n   = ni / 62;
    const uint32_t i   = ni - n * 62;
    uint32_t v = 0;
    if (j < 31) {
        const float* g = gout + (size_t)(n * 256 + o) * HW_GO + i * 62 + 2 * j;
        v = pk_bf16(g[0], g[1]);
    }
    go_ws[t] = v;
}

// ---- pre-pass 2: input fp32 -> X_ws bf16, 16B chunks xor-swizzled by c&7
__global__ __launch_bounds__(256) void x_conv(
    const floatx4* __restrict__ inp, uintx2* __restrict__ x_ws)
{
    const uint32_t t = blockIdx.x * 256 + threadIdx.x;  // < 2,097,152 chunks
    const uint32_t lc = t & 7;               // logical 16B chunk in row
    const uint32_t c7 = (t >> 9) & 7;        // c & 7
    floatx4 v0 = inp[t * 2];
    floatx4 v1 = inp[t * 2 + 1];
    uintx2 o;
    o.x = pk_bf16(v0.x, v0.y) | ((uint64_t)0, 0);  // no-op; keep simple
    o.x = pk_bf16(v0.x, v0.y);
    o.y = pk_bf16(v0.z, v0.w);
    uintx2 p;
    p.x = pk_bf16(v1.x, v1.y);
    p.y = pk_bf16(v1.z, v1.w);
    // one thread handles one 16B chunk = 8 bf16 = 8 floats = 2 floatx4
    uintx2 outv;
    outv.x = o.x; outv.y = o.y;
    // chunk holds floats [t*8 .. t*8+7] -> two uintx2? No: 8 bf16 = 16 B = one uintx2*2
    // 8 bf16 = 16 bytes = {o.x,o.y,p.x,p.y} = 4 dwords. Write as two uintx2.
    const uint32_t base = t & ~7u;
    const uint32_t phys = base | (lc ^ c7);
    uintx2* dst = x_ws + phys * 2;
    uintx2 w0; w0.x = o.x; w0.y = o.y;
    uintx2 w1; w1.x = p.x; w1.y = p.y;
    dst[0] = w0;
    dst[1] = w1;
}

// ---- main: per-chunk partial GEMM, register-derived kw taps
__global__ __launch_bounds__(256, 2) void convbw3_kernel(
    const short* __restrict__ go_ws,   // [n][i][256][72] bf16
    const short* __restrict__ x_ws,    // [n][128][64][64] bf16, swizzled
    float* __restrict__ dst)           // partials, chunk-major
{
    __shared__ __align__(16) short GO_sh[2][128 * 72];  // 2 x 18432 B
    __shared__ __align__(16) short X_sh[2][96 * 64];    // 2 x 12288 B

    const int tid  = threadIdx.x;
    const int lane = tid & 63;
    const int wave = tid >> 6;
    const int l15  = lane & 15;
    const int quad = lane >> 4;

    const int Mbase = blockIdx.x * 128;   // 0,128
    const int Cbase = blockIdx.y * 32;    // 0..96
    const int chunk = blockIdx.z;         // 0..61

    // per-lane invariant parts of DMA source addresses (in shorts)
    const int xlane_off = ((lane >> 3) << 12) + ((lane & 7) << 3);
    const int glane_off = lane << 3;

    auto dma = [&](int u, int buf) {
        const int n_img = u / 62;
        const int i     = u - n_img * 62;
        // GO: 128 rows x 144 B contiguous in GO_ws
        const short* gsrc = go_ws + ((size_t)((n_img * 62 + i) * 256 + Mbase)) * 72;
        short* gdst = &GO_sh[buf][0];
#pragma unroll
        for (int k = wave; k < 18; k += 4)
            load_lds16(gsrc + k * 512 + glane_off, gdst + k * 512);
        // X: 96 rows (kh*32+c) x 128 B, row = [Cbase+c][i+kh], pre-swizzled
        const short* xsrc = x_ws + ((size_t)(n_img * 128 + Cbase) << 12)
                                 + (i << 6);
        short* xdst = &X_sh[buf][0];
#pragma unroll
        for (int b = wave; b < 12; b += 4) {
            const int kh = b >> 2, c0 = (b & 3) * 8;
            load_lds16(xsrc + (c0 << 12) + (kh << 6) + xlane_off,
                       xdst + b * 512);
        }
    };

    floatx4 acc[2][2][9];
#pragma unroll
    for (int mi = 0; mi < 2; ++mi)
#pragma unroll
        for (int ni = 0; ni < 2; ++ni)
#pragma unroll
            for (int t = 0; t < 9; ++t)
                acc[mi][ni][t] = (floatx4){0.f, 0.f, 0.f, 0.f};

    dma(chunk * UNITS, 0);   // prologue

#pragma unroll 1
    for (int uu = 0; uu < UNITS; ++uu) {
        __syncthreads();     // drains DMA(buf cur); all waves past prev MFMA

        if (uu + 1 < UNITS) dma(chunk * UNITS + uu + 1, (uu + 1) & 1);

        const short* Gb = &GO_sh[uu & 1][0];
        const short* Xb = &X_sh[uu & 1][0];

        short8 a[2][2];
#pragma unroll
        for (int mi = 0; mi < 2; ++mi)
#pragma unroll
            for (int ks = 0; ks < 2; ++ks)
                a[mi][ks] = *(const short8*)(Gb + (wave * 32 + mi * 16 + l15) * 72
                                             + ks * 32 + quad * 8);

        const int r7 = l15 & 7;   // row&7 of this lane's X rows (swizzle key)
#pragma unroll
        for (int kh = 0; kh < 3; ++kh) {
#pragma unroll
            for (int ni = 0; ni < 2; ++ni) {
                const short* xrow = Xb + ((kh * 32 + ni * 16 + l15) << 6);
#pragma unroll
                for (int ks = 0; ks < 2; ++ks) {
                    const int lc = ks * 4 + quad;
                    // swizzled, 16B-aligned, conflict-free across the wave
                    const intx4 d =
                        *(const intx4*)(xrow + ((lc ^ r7) << 3));
                    // 5th dword: first dword of next logical chunk (&7 wrap
                    // yields finite garbage only where A cols are zero)
                    const int d4 =
                        *(const int*)(xrow + ((((lc + 1) & 7) ^ r7) << 3));
                    const uint32_t e0 = (uint32_t)d.x, e1 = (uint32_t)d.y,
                                   e2 = (uint32_t)d.z, e3 = (uint32_t)d.w,
                                   e4 = (uint32_t)d4;
                    union { uint32_t u[4]; short8 s; } f0, f1, f2;
                    f0.u[0] = e0; f0.u[1] = e1; f0.u[2] = e2; f0.u[3] = e3;
                    f1.u[0] = (e0 >> 16) | (e1 << 16);
                    f1.u[1] = (e1 >> 16) | (e2 << 16);
                    f1.u[2] = (e2 >> 16) | (e3 << 16);
                    f1.u[3] = (e3 >> 16) | (e4 << 16);
                    f2.u[0] = e1; f2.u[1] = e2; f2.u[2] = e3; f2.u[3] = e4;
#pragma unroll
                    for (int mi = 0; mi < 2; ++mi) {
                        acc[mi][ni][kh * 3 + 0] =
                            __builtin_amdgcn_mfma_f32_16x16x32_bf16(
                                a[mi][ks], f0.s, acc[mi][ni][kh * 3 + 0], 0, 0, 0);
                        acc[mi][ni][kh * 3 + 1] =
                            __builtin_amdgcn_mfma_f32_16x16x32_bf16(
                                a[mi][ks], f1.s, acc[mi][ni][kh * 3 + 1], 0, 0, 0);
                        acc[mi][ni][kh * 3 + 2] =
                            __builtin_amdgcn_mfma_f32_16x16x32_bf16(
                                a[mi][ks], f2.s, acc[mi][ni][kh * 3 + 2], 0, 0, 0);
                    }
                }
            }
        }
    }

    // epilogue: C/D layout col=lane&15, row=quad*4+reg (m89/m91)
    float* base = dst + (size_t)chunk * OUT_ELEMS;
#pragma unroll
    for (int mi = 0; mi < 2; ++mi) {
        const int o_base = Mbase + wave * 32 + mi * 16 + quad * 4;
#pragma unroll
        for (int ni = 0; ni < 2; ++ni) {
            const int c = Cbase + ni * 16 + l15;
#pragma unroll
            for (int t = 0; t < 9; ++t)
#pragma unroll
                for (int r = 0; r < 4; ++r)
                    base[(size_t)(o_base + r) * 1152 + c * 9 + t] =
                        acc[mi][ni][t][r];
        }
    }
}

// ================= fallback (R2 path, ws too small for bf16 staging) ======
template<bool USE_ATOMIC>
__global__ __launch_bounds__(256, 1) void convbw_kernel(
    const float* __restrict__ inp, const float* __restrict__ gout,
    float* __restrict__ dst)
{
    __shared__ __align__(16) short GO_sh[128][72];
    __shared__ __align__(16) short X_sh[3][3][32][72];
    const int tid = threadIdx.x, lane = tid & 63, wave = tid >> 6;
    const int l15 = lane & 15, quad = lane >> 4;
    const int Mbase = blockIdx.x * 128, Cbase = blockIdx.y * 32;
    const int chunk = blockIdx.z;
    const int gl = tid & 31, grow0 = tid >> 5, xl = tid & 15, xrow0 = tid >> 4;
    floatx2 go_r[16];
    floatx4 x_r[6];
    auto issue_loads = [&](int u) {
        const int n_img = u / 62, i = u - n_img * 62;
        const float* bg = gout + (size_t)(n_img * 256 + Mbase) * HW_GO + i * 62;
        const float* bi = inp + (size_t)(n_img * 128 + Cbase) * HW_IN + i * 64;
#pragma unroll
        for (int p = 0; p < 16; ++p)
            go_r[p] = *(const floatx2*)(bg + (size_t)(grow0 + p * 8) * HW_GO + gl * 2);
#pragma unroll
        for (int p = 0; p < 6; ++p) {
            const int row = xrow0 + p * 16, c = row & 31, kh = row >> 5;
            x_r[p] = *(const floatx4*)(bi + (size_t)c * HW_IN + kh * 64 + xl * 4);
        }
    };
    auto flush = [&]() {
#pragma unroll
        for (int p = 0; p < 16; ++p) {
            uint32_t v = pk_bf16(go_r[p].x, go_r[p].y);
            if (gl == 31) v = 0;
            *(uint32_t*)&GO_sh[grow0 + p * 8][gl * 2] = v;
        }
#pragma unroll
        for (int p = 0; p < 6; ++p) {
            const int row = xrow0 + p * 16, c = row & 31, kh = row >> 5;
            uint32_t lo = pk_bf16(x_r[p].x, x_r[p].y);
            uint32_t hi = pk_bf16(x_r[p].z, x_r[p].w);
            uint32_t nlo = (uint32_t)__shfl((int)lo, (lane + 1) & 63);
            uintx2 v0 = {lo, hi};
            uintx2 v1 = {(lo >> 16) | (hi << 16), (hi >> 16) | (nlo << 16)};
            uintx2 v2 = {hi, nlo};
            *(uintx2*)&X_sh[kh][0][c][xl * 4] = v0;
            *(uintx2*)&X_sh[kh][1][c][xl * 4] = v1;
            *(uintx2*)&X_sh[kh][2][c][xl * 4] = v2;
        }
    };
    floatx4 acc[2][2][9];
#pragma unroll
    for (int mi = 0; mi < 2; ++mi)
#pragma unroll
        for (int ni = 0; ni < 2; ++ni)
#pragma unroll
            for (int t = 0; t < 9; ++t) acc[mi][ni][t] = (floatx4){0,0,0,0};
    issue_loads(chunk * UNITS);
#pragma unroll 1
    for (int uu = 0; uu < UNITS; ++uu) {
        flush();
        if (uu + 1 < UNITS) issue_loads(chunk * UNITS + uu + 1);
        __syncthreads();
#pragma unroll
        for (int ks = 0; ks < 2; ++ks) {
            const int kc = ks * 32 + quad * 8;
            const short8 a0 = *(const short8*)&GO_sh[wave * 32 + l15][kc];
            const short8 a1 = *(const short8*)&GO_sh[wave * 32 + 16 + l15][kc];
#pragma unroll
            for (int kh = 0; kh < 3; ++kh)
#pragma unroll
                for (int kw = 0; kw < 3; ++kw) {
                    const int t = kh * 3 + kw;
#pragma unroll
                    for (int ni = 0; ni < 2; ++ni) {
                        const short8 b = *(const short8*)&X_sh[kh][kw][ni * 16 + l15][kc];
                        acc[0][ni][t] = __builtin_amdgcn_mfma_f32_16x16x32_bf16(a0, b, acc[0][ni][t], 0, 0, 0);
                        acc[1][ni][t] = __builtin_amdgcn_mfma_f32_16x16x32_bf16(a1, b, acc[1][ni][t], 0, 0, 0);
                    }
                }
        }
        __syncthreads();
    }
    float* base = USE_ATOMIC ? dst : dst + (size_t)chunk * OUT_ELEMS;
#pragma unroll
    for (int mi = 0; mi < 2; ++mi) {
        const int o_base = Mbase + wave * 32 + mi * 16 + quad * 4;
#pragma unroll
        for (int ni = 0; ni < 2; ++ni) {
            const int c = Cbase + ni * 16 + l15;
#pragma unroll
            for (int t = 0; t < 9; ++t)
#pragma unroll
                for (int r = 0; r < 4; ++r) {
                    const size_t off = (size_t)(o_base + r) * 1152 + c * 9 + t;
                    if (USE_ATOMIC) atomicAdd(base + off, acc[mi][ni][t][r]);
                    else base[off] = acc[mi][ni][t][r];
                }
        }
    }
}

__global__ __launch_bounds__(256) void reduce_kernel(
    const floatx4* __restrict__ ws, floatx4* __restrict__ out)
{
    const int idx = blockIdx.x * 256 + threadIdx.x;
    floatx4 s = {0.f, 0.f, 0.f, 0.f};
#pragma unroll 2
    for (int ch = 0; ch < NCHUNK; ++ch)
        s += ws[(size_t)ch * (OUT_ELEMS / 4) + idx];
    out[idx] = s;
}

extern "C" void kernel_launch(void* const* d_in, const int* in_sizes, int n_in,
                              void* d_out, int out_size, void* d_ws, size_t ws_size,
                              hipStream_t stream) {
    const float* inp  = (const float*)d_in[0];
    const float* gout = (const float*)d_in[1];
    float* out = (float*)d_out;
    dim3 grid(2, 4, NCHUNK);

    if (ws_size >= WS_FULL) {
        float* part = (float*)d_ws;
        short* go_ws = (short*)((char*)d_ws + PART_BYTES);
        short* x_ws  = (short*)((char*)d_ws + PART_BYTES + GOWS_BYTES);
        go_conv<<<71424, 256, 0, stream>>>(gout, (uint32_t*)go_ws);
        x_conv<<<8192, 256, 0, stream>>>((const floatx4*)inp, (uintx2*)x_ws);
        convbw3_kernel<<<grid, 256, 0, stream>>>(go_ws, x_ws, part);
        reduce_kernel<<<OUT_ELEMS / 4 / 256, 256, 0, stream>>>(
            (const floatx4*)part, (floatx4*)out);
    } else if (ws_size >= PART_BYTES) {
        float* part = (float*)d_ws;
        convbw_kernel<false><<<grid, 256, 0, stream>>>(inp, gout, part);
        reduce_kernel<<<OUT_ELEMS / 4 / 256, 256, 0, stream>>>(
            (const floatx4*)part, (floatx4*)out);
    } else {
        hipMemsetAsync(d_out, 0, (size_t)out_size * sizeof(float), stream);
        convbw_kernel<true><<<grid, 256, 0, stream>>>(inp, gout, out);
    }
}